// Round 11
// baseline (12188.442 us; speedup 1.0000x reference)
//
#include <hip/hip_runtime.h>
#include <hip/hip_bf16.h>

#define B_ 256
#define T_ 512
#define D_ 256
#define H_ 1024
#define C_ 10
#define KSPL 448   // gate-2 k-range resident in LDS

typedef __attribute__((ext_vector_type(8))) short short8;
typedef __attribute__((ext_vector_type(4))) float floatx4;

static __device__ __forceinline__ unsigned short f2bf(float f) {
    __hip_bfloat16 b = __float2bfloat16(f);
    return *reinterpret_cast<unsigned short*>(&b);
}
static __device__ __forceinline__ float bf2f(unsigned short u) {
    unsigned int v = ((unsigned int)u) << 16;
    return __uint_as_float(v);
}
static __device__ __forceinline__ float fast_tanh(float x) {
    float e = __expf(2.f * x);
    return 1.f - __fdividef(2.f, e + 1.f);
}

// ---------------------------------------------------------------------------
// Pack Wh gates into WhT[gate][j][k] = bf16(W_gate_h[k][j]) (transposed)
// ---------------------------------------------------------------------------
__global__ void lstm_pack_wht(const float* __restrict__ Wg,
                              const float* __restrict__ Wi,
                              const float* __restrict__ Wf,
                              const float* __restrict__ Wo,
                              unsigned short* __restrict__ WT) {
    __shared__ float tile[32][33];
    int g = blockIdx.z;
    const float* W = (g == 0) ? Wg : (g == 1) ? Wi : (g == 2) ? Wf : Wo;
    int j0 = blockIdx.x * 32;
    int k0 = blockIdx.y * 32;
    int tx = threadIdx.x & 31, ty = threadIdx.x >> 5;  // 32 x 8
    #pragma unroll
    for (int s = 0; s < 32; s += 8)
        tile[ty + s][tx] = W[(size_t)(k0 + ty + s) * H_ + j0 + tx];
    __syncthreads();
    unsigned short* out = WT + ((size_t)g << 20);
    #pragma unroll
    for (int s = 0; s < 32; s += 8)
        out[(size_t)(j0 + ty + s) * 1024 + k0 + tx] = f2bf(tile[tx][ty + s]);
}

// ---------------------------------------------------------------------------
// proj3[v][col] = sum_d emb[v][d] * Wx[d][col] + b[col], col in [0,4096)
// ---------------------------------------------------------------------------
__global__ void lstm_proj3(const float* __restrict__ emb,
                           const float* __restrict__ Wgx, const float* __restrict__ Wix,
                           const float* __restrict__ Wfx, const float* __restrict__ Wox,
                           const float* __restrict__ bg, const float* __restrict__ bi,
                           const float* __restrict__ bf_, const float* __restrict__ bo,
                           float* __restrict__ proj3) {
    int col = blockIdx.x * 256 + threadIdx.x;
    int v = blockIdx.y;
    int gate = col >> 10;
    int j = col & (H_ - 1);
    const float* Wx = (gate == 0) ? Wgx : (gate == 1) ? Wix : (gate == 2) ? Wfx : Wox;
    const float* bb = (gate == 0) ? bg : (gate == 1) ? bi : (gate == 2) ? bf_ : bo;
    float acc = bb[j];
    for (int d = 0; d < D_; ++d)
        acc += emb[v * D_ + d] * Wx[(size_t)d * H_ + j];
    proj3[(size_t)v * 4096 + col] = acc;
}

// ---------------------------------------------------------------------------
// Persistent LSTM recurrence — XCD-local, L2-resident-B edition.
//
// Composition of the two proven transports (r1-r10 evidence):
//  * DATA (h): plain stores -> vmcnt(0); same-XCD plain loads after one
//    vL1 buffer_inv. Proven r10. Rows partitioned by XCD via XCC_ID+slot.
//  * FLAGS: RMW-exchange write + relaxed agent atomic-load poll (LLC path,
//    bypasses L2 both ways). Proven every round r2-r10. No buffer_inv needed
//    for flag freshness -> inv moved OUT of the poll loop (r10's 17 GB
//    writeback storm came from inv-per-poll-iteration).
//  * B capacity (r10's 16.9 GB refetch): streamed B cut from 4 MB/XCD to
//    3.2 MB/XCD (gate-2 k<448 moved to LDS; LDS = 157.5 KB) -> streamed
//    tail is L2-RESIDENT -> near-zero per-step LLC fill traffic.
// ---------------------------------------------------------------------------
__launch_bounds__(256, 1)
__global__ void lstm_persist(const unsigned short* __restrict__ WhT,
                             const float* __restrict__ proj3,
                             const int* __restrict__ x,
                             unsigned short* __restrict__ hb0,
                             unsigned short* __restrict__ hb1,
                             int* __restrict__ flg,      // [T][8][32*4]
                             int* __restrict__ xcdctr) { // [8]
    __shared__ unsigned short Blds[64 * 1024 + 32 * KSPL];  // 157.5 KB
    __shared__ float projL[3][128];
    __shared__ int s_place;

    const int tid = threadIdx.x;

    // ---- self-placement: XCD id + column slot (proven r8/r10) ----
    {
        unsigned int xcc_raw;
        asm volatile("s_getreg_b32 %0, hwreg(HW_REG_XCC_ID)" : "=s"(xcc_raw));
        if (tid == 0) {
            int slot = atomicAdd(&xcdctr[xcc_raw & 7], 1);
            s_place = (int)((xcc_raw & 7) << 5) | (slot & 31);
        }
    }
    __syncthreads();
    const int xcc = s_place >> 5;   // 0..7  -> rows xcc*32..+31
    const int cw  = s_place & 31;   // 0..31 -> hcols cw*32..+31
    const int hc0 = cw * 32;

    // ---- one-time LDS fill: gates 0,1 full K (XOR-swizzled) ----
    {
        const int q2 = tid & 63;           // g*32 + hcol_local
        const int g = q2 >> 5;
        const int hl_ = q2 & 31;
        const int j = hc0 + hl_;
        const int xq = (hl_ & 7) << 3;
        const unsigned short* src = WhT + ((size_t)g << 20) + (size_t)j * 1024;
        const int kb0 = (tid >> 6) * 256;
        #pragma unroll
        for (int it = 0; it < 32; ++it) {
            int k = kb0 + 8 * it;
            *(short8*)(Blds + (size_t)(g * 32 + hl_) * 1024 + (k ^ xq)) =
                *(const short8*)(src + k);
        }
    }
    // ---- one-time LDS fill: gate 2, k in [0, KSPL) ----
    {
        const unsigned short* src2 = WhT + ((size_t)2 << 20);
        unsigned short* G2 = Blds + 64 * 1024;
        for (int idx = tid; idx < 32 * (KSPL / 8); idx += 256) {  // 1792
            int col = idx / (KSPL / 8);
            int k = (idx - col * (KSPL / 8)) * 8;
            int xq = (col & 7) << 3;
            *(short8*)(G2 + (size_t)col * KSPL + (k ^ xq)) =
                *(const short8*)(src2 + (size_t)(hc0 + col) * 1024 + k);
        }
    }
    for (int idx = tid; idx < 384; idx += 256) {
        int v = idx >> 7, q = idx & 127;
        projL[v][q] = proj3[(size_t)v * 4096 + (size_t)(q >> 5) * 1024 + hc0 + (q & 31)];
    }
    __syncthreads();

    // ---- wave/lane geometry (r10-proven) ----
    const int w = tid >> 6;
    const int wr = w >> 1;             // row-slab 0,1 (16 rows)
    const int wc = w & 1;              // hcol-group 0,1 (16 hcols)
    const int lane = tid & 63;
    const int lr = lane & 15;
    const int kq = lane >> 4;          // 0..3
    const int R0 = xcc * 32 + 16 * wr;
    const int hl = 16 * wc + lr;       // hcol_local 0..31
    const int xorq = (hl & 7) << 3;
    const size_t abase = (size_t)(R0 + lr) * H_ + 8 * kq;
    const int crow0 = R0 + 4 * kq;

    const unsigned short* BL0 = Blds + (size_t)hl * 1024;          // gate 0
    const unsigned short* BL1 = Blds + (size_t)(32 + hl) * 1024;   // gate 1
    const unsigned short* BL2 = Blds + 64 * 1024 + (size_t)hl * KSPL;  // gate 2 head
    const unsigned short* BS2 = WhT + ((size_t)2 << 20) + (size_t)(hc0 + hl) * 1024 + 8 * kq;
    const unsigned short* BS3 = WhT + ((size_t)3 << 20) + (size_t)(hc0 + hl) * 1024 + 8 * kq;

    float creg[4] = {0.f, 0.f, 0.f, 0.f};
    unsigned short* hbuf[2] = {hb0, hb1};

    for (int t = 0; t < T_; ++t) {
        const unsigned short* h_in = hbuf[t & 1];
        unsigned short* h_out = hbuf[(t + 1) & 1];

        // tokens: immutable input, issue before the poll
        int tok[4];
        #pragma unroll
        for (int i = 0; i < 4; ++i)
            tok[i] = x[(size_t)(crow0 + i) * T_ + t];

        if (t > 0) {
            // poll this XCD's 32 WG-flags via the LLC (atomic loads, 16B stride)
            const int* fa = flg + ((size_t)(t - 1) * 8 + xcc) * 128;
            while (true) {
                int v = 1;
                if (lane < 32)
                    v = __hip_atomic_load(fa + lane * 4, __ATOMIC_RELAXED,
                                          __HIP_MEMORY_SCOPE_AGENT);
                if (__all(v != 0)) break;
                __builtin_amdgcn_s_sleep(1);
            }
            // ONE vL1 flash-invalidate: h loads below then hit the shared L2
            asm volatile("buffer_inv" ::: "memory");
        }

        // ---- A preload: plain loads, served by this XCD's L2 ----
        short8 af[32];
        #pragma unroll
        for (int k2 = 0; k2 < 32; ++k2)
            af[k2] = *(const short8*)(h_in + abase + 32 * k2);

        // ---- GEMM: z[16 rows x 4 gates x 16 hcols], K=1024 ----
        floatx4 acc[4] = {};
        #pragma unroll 7
        for (int k2 = 0; k2 < 14; ++k2) {           // k < 448: g2 from LDS
            int ki = (32 * k2 + 8 * kq) ^ xorq;
            short8 b0 = *(const short8*)(BL0 + ki);
            short8 b1 = *(const short8*)(BL1 + ki);
            short8 b2 = *(const short8*)(BL2 + ki);
            short8 b3 = *(const short8*)(BS3 + 32 * k2);
            acc[0] = __builtin_amdgcn_mfma_f32_16x16x32_bf16(af[k2], b0, acc[0], 0, 0, 0);
            acc[1] = __builtin_amdgcn_mfma_f32_16x16x32_bf16(af[k2], b1, acc[1], 0, 0, 0);
            acc[2] = __builtin_amdgcn_mfma_f32_16x16x32_bf16(af[k2], b2, acc[2], 0, 0, 0);
            acc[3] = __builtin_amdgcn_mfma_f32_16x16x32_bf16(af[k2], b3, acc[3], 0, 0, 0);
        }
        #pragma unroll 6
        for (int k2 = 14; k2 < 32; ++k2) {          // k >= 448: g2 streamed (L2)
            int ki = (32 * k2 + 8 * kq) ^ xorq;
            short8 b0 = *(const short8*)(BL0 + ki);
            short8 b1 = *(const short8*)(BL1 + ki);
            short8 b2 = *(const short8*)(BS2 + 32 * k2);
            short8 b3 = *(const short8*)(BS3 + 32 * k2);
            acc[0] = __builtin_amdgcn_mfma_f32_16x16x32_bf16(af[k2], b0, acc[0], 0, 0, 0);
            acc[1] = __builtin_amdgcn_mfma_f32_16x16x32_bf16(af[k2], b1, acc[1], 0, 0, 0);
            acc[2] = __builtin_amdgcn_mfma_f32_16x16x32_bf16(af[k2], b2, acc[2], 0, 0, 0);
            acc[3] = __builtin_amdgcn_mfma_f32_16x16x32_bf16(af[k2], b3, acc[3], 0, 0, 0);
        }

        // ---- in-register combine; plain 2B stores (land in shared L2) ----
        #pragma unroll
        for (int i = 0; i < 4; ++i) {
            const float* pl = projL[tok[i]];
            float zg = fast_tanh(acc[0][i] + pl[hl]);
            float zi = fast_tanh(acc[1][i] + pl[32 + hl]);
            float zf = fast_tanh(acc[2][i] + pl[64 + hl]);
            float zo = fast_tanh(acc[3][i] + pl[96 + hl]);
            float cv = zg * zi + creg[i] * zf;
            creg[i] = cv;
            h_out[(size_t)(crow0 + i) * H_ + hc0 + hl] = f2bf(fast_tanh(cv) * zo);
        }

        if (t == T_ - 1) break;  // kernel-end writeback covers lstm_final

        // ---- release: stores acked at L2 -> flag RMW at the LLC ----
        asm volatile("s_waitcnt vmcnt(0)" ::: "memory");
        __syncthreads();  // all 4 waves' stores drained
        if (tid == 0)
            __hip_atomic_exchange(flg + ((size_t)t * 8 + xcc) * 128 + cw * 4, 1,
                                  __ATOMIC_RELAXED, __HIP_MEMORY_SCOPE_AGENT);
    }
}

// ---------------------------------------------------------------------------
// Final projection + log_softmax. One block (64 threads) per batch row.
// ---------------------------------------------------------------------------
__global__ void lstm_final(const unsigned short* __restrict__ h,
                           const float* __restrict__ Wp,
                           const float* __restrict__ bp,
                           float* __restrict__ out) {
    int row = blockIdx.x;
    int lane = threadIdx.x;
    float acc[C_];
    #pragma unroll
    for (int cc = 0; cc < C_; ++cc) acc[cc] = 0.f;
    for (int k = lane; k < H_; k += 64) {
        float hv = bf2f(h[(size_t)row * H_ + k]);
        #pragma unroll
        for (int cc = 0; cc < C_; ++cc) acc[cc] += hv * Wp[(size_t)k * C_ + cc];
    }
    #pragma unroll
    for (int cc = 0; cc < C_; ++cc)
        #pragma unroll
        for (int off = 32; off > 0; off >>= 1)
            acc[cc] += __shfl_down(acc[cc], off);
    if (lane == 0) {
        float p[C_];
        float m = -1e30f;
        #pragma unroll
        for (int cc = 0; cc < C_; ++cc) {
            p[cc] = acc[cc] + bp[cc];
            m = fmaxf(m, p[cc]);
        }
        float se = 0.f;
        #pragma unroll
        for (int cc = 0; cc < C_; ++cc) se += expf(p[cc] - m);
        float lse = m + logf(se);
        #pragma unroll
        for (int cc = 0; cc < C_; ++cc) out[(size_t)row * C_ + cc] = p[cc] - lse;
    }
}

extern "C" void kernel_launch(void* const* d_in, const int* in_sizes, int n_in,
                              void* d_out, int out_size, void* d_ws, size_t ws_size,
                              hipStream_t stream) {
    const int* x = (const int*)d_in[0];
    const float* emb = (const float*)d_in[1];
    const float* W_gx = (const float*)d_in[2];
    const float* W_gh = (const float*)d_in[3];
    const float* b_g = (const float*)d_in[4];
    const float* W_ix = (const float*)d_in[5];
    const float* W_ih = (const float*)d_in[6];
    const float* b_i = (const float*)d_in[7];
    const float* W_fx = (const float*)d_in[8];
    const float* W_fh = (const float*)d_in[9];
    const float* b_f = (const float*)d_in[10];
    const float* W_ox = (const float*)d_in[11];
    const float* W_oh = (const float*)d_in[12];
    const float* b_o = (const float*)d_in[13];
    const float* W_ph = (const float*)d_in[14];
    const float* b_p = (const float*)d_in[15];
    float* out = (float*)d_out;

    // workspace layout
    char* ws = (char*)d_ws;
    unsigned short* WhT = (unsigned short*)ws;                   // 8 MB
    size_t off = (size_t)4 * 1024 * 1024 * 2;
    float* proj3 = (float*)(ws + off); off += 3 * 4096 * 4;      // 48 KB
    unsigned short* hbuf0 = (unsigned short*)(ws + off); off += (size_t)B_ * H_ * 2;
    unsigned short* hbuf1 = (unsigned short*)(ws + off); off += (size_t)B_ * H_ * 2;
    int* flg = (int*)(ws + off); off += (size_t)T_ * 8 * 128 * 4;  // 2 MB
    int* xcdctr = (int*)(ws + off); off += 8 * sizeof(int);

    // 1. pack WhT (bf16, transposed)
    lstm_pack_wht<<<dim3(32, 32, 4), 256, 0, stream>>>(W_gh, W_ih, W_fh, W_oh, WhT);
    // 2. proj3 = emb @ Wx + b
    lstm_proj3<<<dim3(16, 3), 256, 0, stream>>>(emb, W_gx, W_ix, W_fx, W_ox,
                                                b_g, b_i, b_f, b_o, proj3);
    // 3. zero h0, flags, slot counters (every launch -> replay-safe)
    hipMemsetAsync(hbuf0, 0, (size_t)B_ * H_ * 2, stream);
    hipMemsetAsync(flg, 0, (size_t)T_ * 8 * 128 * 4, stream);
    hipMemsetAsync(xcdctr, 0, 8 * sizeof(int), stream);

    // 4. persistent recurrence (cooperative: all 256 WGs co-resident)
    {
        const unsigned short* a0 = WhT;
        const float* a1 = proj3; const int* a2 = x;
        unsigned short* a3 = hbuf0; unsigned short* a4 = hbuf1;
        int* a5 = flg; int* a6 = xcdctr;
        void* args[] = {&a0, &a1, &a2, &a3, &a4, &a5, &a6};
        hipLaunchCooperativeKernel((const void*)lstm_persist, dim3(256), dim3(256),
                                   args, 0, stream);
    }

    // 5. final projection + log_softmax (h_512 lands in hbuf0: T_ even)
    lstm_final<<<B_, 64, 0, stream>>>(hbuf0, W_ph, b_p, out);
}

// Round 13
// 5612.123 us; speedup vs baseline: 2.1718x; 2.1718x over previous
//
#include <hip/hip_runtime.h>
#include <hip/hip_bf16.h>

#define B_ 256
#define T_ 512
#define D_ 256
#define H_ 1024
#define C_ 10
#define KSPL 448   // gate-2 k-range resident in LDS

typedef __attribute__((ext_vector_type(8))) short short8;
typedef __attribute__((ext_vector_type(4))) float floatx4;

static __device__ __forceinline__ unsigned short f2bf(float f) {
    __hip_bfloat16 b = __float2bfloat16(f);
    return *reinterpret_cast<unsigned short*>(&b);
}
static __device__ __forceinline__ float bf2f(unsigned short u) {
    unsigned int v = ((unsigned int)u) << 16;
    return __uint_as_float(v);
}
static __device__ __forceinline__ float fast_tanh(float x) {
    float e = __expf(2.f * x);
    return 1.f - __fdividef(2.f, e + 1.f);
}

// ---------------------------------------------------------------------------
// Pack Wh gates into WhT[gate][j][k] = bf16(W_gate_h[k][j]) (transposed)
// ---------------------------------------------------------------------------
__global__ void lstm_pack_wht(const float* __restrict__ Wg,
                              const float* __restrict__ Wi,
                              const float* __restrict__ Wf,
                              const float* __restrict__ Wo,
                              unsigned short* __restrict__ WT) {
    __shared__ float tile[32][33];
    int g = blockIdx.z;
    const float* W = (g == 0) ? Wg : (g == 1) ? Wi : (g == 2) ? Wf : Wo;
    int j0 = blockIdx.x * 32;
    int k0 = blockIdx.y * 32;
    int tx = threadIdx.x & 31, ty = threadIdx.x >> 5;  // 32 x 8
    #pragma unroll
    for (int s = 0; s < 32; s += 8)
        tile[ty + s][tx] = W[(size_t)(k0 + ty + s) * H_ + j0 + tx];
    __syncthreads();
    unsigned short* out = WT + ((size_t)g << 20);
    #pragma unroll
    for (int s = 0; s < 32; s += 8)
        out[(size_t)(j0 + ty + s) * 1024 + k0 + tx] = f2bf(tile[tx][ty + s]);
}

// ---------------------------------------------------------------------------
// proj3[v][col] = sum_d emb[v][d] * Wx[d][col] + b[col], col in [0,4096)
// ---------------------------------------------------------------------------
__global__ void lstm_proj3(const float* __restrict__ emb,
                           const float* __restrict__ Wgx, const float* __restrict__ Wix,
                           const float* __restrict__ Wfx, const float* __restrict__ Wox,
                           const float* __restrict__ bg, const float* __restrict__ bi,
                           const float* __restrict__ bf_, const float* __restrict__ bo,
                           float* __restrict__ proj3) {
    int col = blockIdx.x * 256 + threadIdx.x;
    int v = blockIdx.y;
    int gate = col >> 10;
    int j = col & (H_ - 1);
    const float* Wx = (gate == 0) ? Wgx : (gate == 1) ? Wix : (gate == 2) ? Wfx : Wox;
    const float* bb = (gate == 0) ? bg : (gate == 1) ? bi : (gate == 2) ? bf_ : bo;
    float acc = bb[j];
    for (int d = 0; d < D_; ++d)
        acc += emb[v * D_ + d] * Wx[(size_t)d * H_ + j];
    proj3[(size_t)v * 4096 + col] = acc;
}

// ---------------------------------------------------------------------------
// Persistent LSTM recurrence — XCD-local, chunked-sc0-load edition.
//
// r12 post-mortem: the single-shot 32x sc0 asm preload forced 128 VGPRs of
// asm outputs live behind sched_barrier walls -> register spilling; a spill
// store reads the asm dest BEFORE the async load retires -> garbage A
// (absmax 5.44, distinct from the h==0 signature 1.86). Fix: 4 chunks of 8
// loads, double-buffered af[2][8] (64 VGPR max), counted vmcnt(8) pipeline,
// "=&v" early-clobber.
//
// Coherence (zero cache-maintenance ops in the loop; r10/r11-proven base):
//  * h producer: plain stores (write-through vL1, dirty in shared XCD L2)
//  * h consumer: `global_load_dwordx4 ... sc0` = SE-scope load: bypasses
//    vL1 per-instruction, served by the XCD L2 (agent atomics = sc0+sc1
//    skip to LLC and miss dirty L2 — proven failure r4-r7; bare buffer_inv
//    wipes the L2 -> 33 GB/step traffic storm — proven r10/r11).
//  * flags: agent-atomic RMW + atomic-load poll at the LLC (proven r2-r11).
// Rows partitioned by XCD via XCC_ID + slot counter (proven r8/r10/r11).
// ---------------------------------------------------------------------------
__launch_bounds__(256, 1)
__global__ void lstm_persist(const unsigned short* __restrict__ WhT,
                             const float* __restrict__ proj3,
                             const int* __restrict__ x,
                             unsigned short* __restrict__ hb0,
                             unsigned short* __restrict__ hb1,
                             int* __restrict__ flg,      // [T][8][32*4]
                             int* __restrict__ xcdctr) { // [8]
    __shared__ unsigned short Blds[64 * 1024 + 32 * KSPL];  // 157.5 KB
    __shared__ float projL[3][128];
    __shared__ int s_place;

    const int tid = threadIdx.x;

    // ---- self-placement: XCD id + column slot (proven r8/r10/r11) ----
    {
        unsigned int xcc_raw;
        asm volatile("s_getreg_b32 %0, hwreg(HW_REG_XCC_ID)" : "=s"(xcc_raw));
        if (tid == 0) {
            int slot = atomicAdd(&xcdctr[xcc_raw & 7], 1);
            s_place = (int)((xcc_raw & 7) << 5) | (slot & 31);
        }
    }
    __syncthreads();
    const int xcc = s_place >> 5;   // 0..7  -> rows xcc*32..+31
    const int cw  = s_place & 31;   // 0..31 -> hcols cw*32..+31
    const int hc0 = cw * 32;

    // ---- one-time LDS fill: gates 0,1 full K (XOR-swizzled) ----
    {
        const int q2 = tid & 63;           // g*32 + hcol_local
        const int g = q2 >> 5;
        const int hl_ = q2 & 31;
        const int j = hc0 + hl_;
        const int xq = (hl_ & 7) << 3;
        const unsigned short* src = WhT + ((size_t)g << 20) + (size_t)j * 1024;
        const int kb0 = (tid >> 6) * 256;
        #pragma unroll
        for (int it = 0; it < 32; ++it) {
            int k = kb0 + 8 * it;
            *(short8*)(Blds + (size_t)(g * 32 + hl_) * 1024 + (k ^ xq)) =
                *(const short8*)(src + k);
        }
    }
    // ---- one-time LDS fill: gate 2, k in [0, KSPL) ----
    {
        const unsigned short* src2 = WhT + ((size_t)2 << 20);
        unsigned short* G2 = Blds + 64 * 1024;
        for (int idx = tid; idx < 32 * (KSPL / 8); idx += 256) {  // 1792
            int col = idx / (KSPL / 8);
            int k = (idx - col * (KSPL / 8)) * 8;
            int xq = (col & 7) << 3;
            *(short8*)(G2 + (size_t)col * KSPL + (k ^ xq)) =
                *(const short8*)(src2 + (size_t)(hc0 + col) * 1024 + k);
        }
    }
    for (int idx = tid; idx < 384; idx += 256) {
        int v = idx >> 7, q = idx & 127;
        projL[v][q] = proj3[(size_t)v * 4096 + (size_t)(q >> 5) * 1024 + hc0 + (q & 31)];
    }
    __syncthreads();

    // ---- wave/lane geometry (r10/r11-proven) ----
    const int w = tid >> 6;
    const int wr = w >> 1;             // row-slab 0,1 (16 rows)
    const int wc = w & 1;              // hcol-group 0,1 (16 hcols)
    const int lane = tid & 63;
    const int lr = lane & 15;
    const int kq = lane >> 4;          // 0..3
    const int R0 = xcc * 32 + 16 * wr;
    const int hl = 16 * wc + lr;       // hcol_local 0..31
    const int xorq = (hl & 7) << 3;
    const size_t abase = (size_t)(R0 + lr) * H_ + 8 * kq;
    const int crow0 = R0 + 4 * kq;

    const unsigned short* BL0 = Blds + (size_t)hl * 1024;          // gate 0
    const unsigned short* BL1 = Blds + (size_t)(32 + hl) * 1024;   // gate 1
    const unsigned short* BL2 = Blds + 64 * 1024 + (size_t)hl * KSPL;  // gate 2 head
    const unsigned short* BS2 = WhT + ((size_t)2 << 20) + (size_t)(hc0 + hl) * 1024 + 8 * kq;
    const unsigned short* BS3 = WhT + ((size_t)3 << 20) + (size_t)(hc0 + hl) * 1024 + 8 * kq;

    float creg[4] = {0.f, 0.f, 0.f, 0.f};
    unsigned short* hbuf[2] = {hb0, hb1};

    for (int t = 0; t < T_; ++t) {
        const unsigned short* h_in = hbuf[t & 1];
        unsigned short* h_out = hbuf[(t + 1) & 1];

        // tokens: immutable input, issue before the poll
        int tok[4];
        #pragma unroll
        for (int i = 0; i < 4; ++i)
            tok[i] = x[(size_t)(crow0 + i) * T_ + t];

        if (t > 0) {
            // poll this XCD's 32 WG-flags via the LLC (atomic loads, 16B stride)
            const int* fa = flg + ((size_t)(t - 1) * 8 + xcc) * 128;
            while (true) {
                int v = 1;
                if (lane < 32)
                    v = __hip_atomic_load(fa + lane * 4, __ATOMIC_RELAXED,
                                          __HIP_MEMORY_SCOPE_AGENT);
                if (__all(v != 0)) break;
                __builtin_amdgcn_s_sleep(1);
            }
            asm volatile("" ::: "memory");  // no data-load hoisting above poll
        }

        // ---- GEMM with chunked sc0 A-pipeline: 4 chunks x 8 k2 ----
        // sc0 loads bypass vL1, served by shared XCD L2 (fresh h).
        const unsigned short* aptr = h_in + abase;
        short8 afA[8], afB[8];

        // issue chunk 0 -> afA
        #pragma unroll
        for (int j = 0; j < 8; ++j)
            asm volatile("global_load_dwordx4 %0, %1, off offset:%2 sc0"
                         : "=&v"(afA[j]) : "v"(aptr), "n"(64 * j));

        floatx4 acc[4] = {};
        #pragma unroll
        for (int c = 0; c < 4; ++c) {
            // issue next chunk into the other buffer
            if (c < 3) {
                if ((c & 1) == 0) {
                    #pragma unroll
                    for (int j = 0; j < 8; ++j)
                        asm volatile("global_load_dwordx4 %0, %1, off offset:%2 sc0"
                                     : "=&v"(afB[j]) : "v"(aptr), "n"(64 * (8 * (c + 1) + j)));
                } else {
                    #pragma unroll
                    for (int j = 0; j < 8; ++j)
                        asm volatile("global_load_dwordx4 %0, %1, off offset:%2 sc0"
                                     : "=&v"(afA[j]) : "v"(aptr), "n"(64 * (8 * (c + 1) + j)));
                }
                __builtin_amdgcn_sched_barrier(0);
                asm volatile("s_waitcnt vmcnt(8)" ::: "memory");  // chunk c retired
                __builtin_amdgcn_sched_barrier(0);
            } else {
                __builtin_amdgcn_sched_barrier(0);
                asm volatile("s_waitcnt vmcnt(0)" ::: "memory");
                __builtin_amdgcn_sched_barrier(0);
            }
            #pragma unroll
            for (int j = 0; j < 8; ++j) {
                const int k2 = 8 * c + j;
                const short8 a = ((c & 1) == 0) ? afA[j] : afB[j];
                const int ki = (32 * k2 + 8 * kq) ^ xorq;
                short8 b0 = *(const short8*)(BL0 + ki);
                short8 b1 = *(const short8*)(BL1 + ki);
                short8 b2, b3;
                if (k2 < 14) b2 = *(const short8*)(BL2 + ki);
                else         b2 = *(const short8*)(BS2 + 32 * k2);
                b3 = *(const short8*)(BS3 + 32 * k2);
                acc[0] = __builtin_amdgcn_mfma_f32_16x16x32_bf16(a, b0, acc[0], 0, 0, 0);
                acc[1] = __builtin_amdgcn_mfma_f32_16x16x32_bf16(a, b1, acc[1], 0, 0, 0);
                acc[2] = __builtin_amdgcn_mfma_f32_16x16x32_bf16(a, b2, acc[2], 0, 0, 0);
                acc[3] = __builtin_amdgcn_mfma_f32_16x16x32_bf16(a, b3, acc[3], 0, 0, 0);
            }
        }

        // ---- in-register combine; plain 2B stores (land in shared L2) ----
        #pragma unroll
        for (int i = 0; i < 4; ++i) {
            const float* pl = projL[tok[i]];
            float zg = fast_tanh(acc[0][i] + pl[hl]);
            float zi = fast_tanh(acc[1][i] + pl[32 + hl]);
            float zf = fast_tanh(acc[2][i] + pl[64 + hl]);
            float zo = fast_tanh(acc[3][i] + pl[96 + hl]);
            float cv = zg * zi + creg[i] * zf;
            creg[i] = cv;
            h_out[(size_t)(crow0 + i) * H_ + hc0 + hl] = f2bf(fast_tanh(cv) * zo);
        }

        if (t == T_ - 1) break;  // end-of-dispatch release covers lstm_final

        // ---- release: stores acked at L2 -> flag RMW at the LLC ----
        asm volatile("s_waitcnt vmcnt(0)" ::: "memory");
        __syncthreads();  // all 4 waves' stores drained
        if (tid == 0)
            __hip_atomic_exchange(flg + ((size_t)t * 8 + xcc) * 128 + cw * 4, 1,
                                  __ATOMIC_RELAXED, __HIP_MEMORY_SCOPE_AGENT);
    }
}

// ---------------------------------------------------------------------------
// Final projection + log_softmax. One block (64 threads) per batch row.
// ---------------------------------------------------------------------------
__global__ void lstm_final(const unsigned short* __restrict__ h,
                           const float* __restrict__ Wp,
                           const float* __restrict__ bp,
                           float* __restrict__ out) {
    int row = blockIdx.x;
    int lane = threadIdx.x;
    float acc[C_];
    #pragma unroll
    for (int cc = 0; cc < C_; ++cc) acc[cc] = 0.f;
    for (int k = lane; k < H_; k += 64) {
        float hv = bf2f(h[(size_t)row * H_ + k]);
        #pragma unroll
        for (int cc = 0; cc < C_; ++cc) acc[cc] += hv * Wp[(size_t)k * C_ + cc];
    }
    #pragma unroll
    for (int cc = 0; cc < C_; ++cc)
        #pragma unroll
        for (int off = 32; off > 0; off >>= 1)
            acc[cc] += __shfl_down(acc[cc], off);
    if (lane == 0) {
        float p[C_];
        float m = -1e30f;
        #pragma unroll
        for (int cc = 0; cc < C_; ++cc) {
            p[cc] = acc[cc] + bp[cc];
            m = fmaxf(m, p[cc]);
        }
        float se = 0.f;
        #pragma unroll
        for (int cc = 0; cc < C_; ++cc) se += expf(p[cc] - m);
        float lse = m + logf(se);
        #pragma unroll
        for (int cc = 0; cc < C_; ++cc) out[(size_t)row * C_ + cc] = p[cc] - lse;
    }
}

extern "C" void kernel_launch(void* const* d_in, const int* in_sizes, int n_in,
                              void* d_out, int out_size, void* d_ws, size_t ws_size,
                              hipStream_t stream) {
    const int* x = (const int*)d_in[0];
    const float* emb = (const float*)d_in[1];
    const float* W_gx = (const float*)d_in[2];
    const float* W_gh = (const float*)d_in[3];
    const float* b_g = (const float*)d_in[4];
    const float* W_ix = (const float*)d_in[5];
    const float* W_ih = (const float*)d_in[6];
    const float* b_i = (const float*)d_in[7];
    const float* W_fx = (const float*)d_in[8];
    const float* W_fh = (const float*)d_in[9];
    const float* b_f = (const float*)d_in[10];
    const float* W_ox = (const float*)d_in[11];
    const float* W_oh = (const float*)d_in[12];
    const float* b_o = (const float*)d_in[13];
    const float* W_ph = (const float*)d_in[14];
    const float* b_p = (const float*)d_in[15];
    float* out = (float*)d_out;

    // workspace layout
    char* ws = (char*)d_ws;
    unsigned short* WhT = (unsigned short*)ws;                   // 8 MB
    size_t off = (size_t)4 * 1024 * 1024 * 2;
    float* proj3 = (float*)(ws + off); off += 3 * 4096 * 4;      // 48 KB
    unsigned short* hbuf0 = (unsigned short*)(ws + off); off += (size_t)B_ * H_ * 2;
    unsigned short* hbuf1 = (unsigned short*)(ws + off); off += (size_t)B_ * H_ * 2;
    int* flg = (int*)(ws + off); off += (size_t)T_ * 8 * 128 * 4;  // 2 MB
    int* xcdctr = (int*)(ws + off); off += 8 * sizeof(int);

    // 1. pack WhT (bf16, transposed)
    lstm_pack_wht<<<dim3(32, 32, 4), 256, 0, stream>>>(W_gh, W_ih, W_fh, W_oh, WhT);
    // 2. proj3 = emb @ Wx + b
    lstm_proj3<<<dim3(16, 3), 256, 0, stream>>>(emb, W_gx, W_ix, W_fx, W_ox,
                                                b_g, b_i, b_f, b_o, proj3);
    // 3. zero h0, flags, slot counters (every launch -> replay-safe)
    hipMemsetAsync(hbuf0, 0, (size_t)B_ * H_ * 2, stream);
    hipMemsetAsync(flg, 0, (size_t)T_ * 8 * 128 * 4, stream);
    hipMemsetAsync(xcdctr, 0, 8 * sizeof(int), stream);

    // 4. persistent recurrence (cooperative: all 256 WGs co-resident)
    {
        const unsigned short* a0 = WhT;
        const float* a1 = proj3; const int* a2 = x;
        unsigned short* a3 = hbuf0; unsigned short* a4 = hbuf1;
        int* a5 = flg; int* a6 = xcdctr;
        void* args[] = {&a0, &a1, &a2, &a3, &a4, &a5, &a6};
        hipLaunchCooperativeKernel((const void*)lstm_persist, dim3(256), dim3(256),
                                   args, 0, stream);
    }

    // 5. final projection + log_softmax (h_512 lands in hbuf0: T_ even)
    lstm_final<<<B_, 64, 0, stream>>>(hbuf0, W_ph, b_p, out);
}

// Round 15
// 5508.132 us; speedup vs baseline: 2.2128x; 1.0189x over previous
//
#include <hip/hip_runtime.h>
#include <hip/hip_bf16.h>

#define B_ 256
#define T_ 512
#define D_ 256
#define H_ 1024
#define C_ 10
#define KSPL 448   // gate-2 k-range resident in LDS

typedef __attribute__((ext_vector_type(8))) short short8;
typedef __attribute__((ext_vector_type(4))) float floatx4;

static __device__ __forceinline__ unsigned short f2bf(float f) {
    __hip_bfloat16 b = __float2bfloat16(f);
    return *reinterpret_cast<unsigned short*>(&b);
}
static __device__ __forceinline__ float bf2f(unsigned short u) {
    unsigned int v = ((unsigned int)u) << 16;
    return __uint_as_float(v);
}
static __device__ __forceinline__ float fast_tanh(float x) {
    float e = __expf(2.f * x);
    return 1.f - __fdividef(2.f, e + 1.f);
}

// ---------------------------------------------------------------------------
// Pack Wh gates into WhT[gate][j][k] = bf16(W_gate_h[k][j]) (transposed)
// ---------------------------------------------------------------------------
__global__ void lstm_pack_wht(const float* __restrict__ Wg,
                              const float* __restrict__ Wi,
                              const float* __restrict__ Wf,
                              const float* __restrict__ Wo,
                              unsigned short* __restrict__ WT) {
    __shared__ float tile[32][33];
    int g = blockIdx.z;
    const float* W = (g == 0) ? Wg : (g == 1) ? Wi : (g == 2) ? Wf : Wo;
    int j0 = blockIdx.x * 32;
    int k0 = blockIdx.y * 32;
    int tx = threadIdx.x & 31, ty = threadIdx.x >> 5;  // 32 x 8
    #pragma unroll
    for (int s = 0; s < 32; s += 8)
        tile[ty + s][tx] = W[(size_t)(k0 + ty + s) * H_ + j0 + tx];
    __syncthreads();
    unsigned short* out = WT + ((size_t)g << 20);
    #pragma unroll
    for (int s = 0; s < 32; s += 8)
        out[(size_t)(j0 + ty + s) * 1024 + k0 + tx] = f2bf(tile[tx][ty + s]);
}

// ---------------------------------------------------------------------------
// proj3[v][col] = sum_d emb[v][d] * Wx[d][col] + b[col], col in [0,4096)
// ---------------------------------------------------------------------------
__global__ void lstm_proj3(const float* __restrict__ emb,
                           const float* __restrict__ Wgx, const float* __restrict__ Wix,
                           const float* __restrict__ Wfx, const float* __restrict__ Wox,
                           const float* __restrict__ bg, const float* __restrict__ bi,
                           const float* __restrict__ bf_, const float* __restrict__ bo,
                           float* __restrict__ proj3) {
    int col = blockIdx.x * 256 + threadIdx.x;
    int v = blockIdx.y;
    int gate = col >> 10;
    int j = col & (H_ - 1);
    const float* Wx = (gate == 0) ? Wgx : (gate == 1) ? Wix : (gate == 2) ? Wfx : Wox;
    const float* bb = (gate == 0) ? bg : (gate == 1) ? bi : (gate == 2) ? bf_ : bo;
    float acc = bb[j];
    for (int d = 0; d < D_; ++d)
        acc += emb[v * D_ + d] * Wx[(size_t)d * H_ + j];
    proj3[(size_t)v * 4096 + col] = acc;
}

// ---------------------------------------------------------------------------
// Persistent LSTM recurrence — r13 base + aggregated per-XCD counter sync.
//
// r14 post-mortem: routing FLAGS through the same-XCD L2 (plain store + sc0
// poll) deadlocked — polled, replay-reused flag lines are not provably
// coherent on that path. REVERTED to the LLC atomic transport proven in
// every working round (r2-r13): producer RMW + atomic-load poll.
//
// r13's residual 9us/step suspect: 8192 concurrent lane-polls congesting
// the LLC. This round aggregates to ONE counter per XCD per step (own 128B
// line): producer = 1 atomicAdd per WG (32 RMWs/line/step, pipelined);
// consumer = tid0-only poll (256 pollers on 8 lines, 32x less traffic),
// then __syncthreads releases the WG.
//
// Data design (r13-proven, unchanged):
//  * h: plain stores -> dirty in shared XCD L2; consumed by sc0 loads
//    (bypass vL1, served by L2). Rows partitioned by XCD via XCC_ID+slot.
//  * A-pipeline: 4 chunks x 8 sc0 loads, double-buffered, counted vmcnt(8).
//  * B: gates 0,1 + gate-2 head in LDS (157.5 KB); tail L2-resident
//    (FETCH 36 MB total — validated r13).
//  * Ordering: producer h stores acked (vmcnt 0) BEFORE its atomicAdd can
//    be observed -> consumer's same-L2 sc0 loads see fresh h.
// ---------------------------------------------------------------------------
__launch_bounds__(256, 1)
__global__ void lstm_persist(const unsigned short* __restrict__ WhT,
                             const float* __restrict__ proj3,
                             const int* __restrict__ x,
                             unsigned short* __restrict__ hb0,
                             unsigned short* __restrict__ hb1,
                             int* __restrict__ cnt,      // [T][8][32-int pad]
                             int* __restrict__ xcdctr) { // [8]
    __shared__ unsigned short Blds[64 * 1024 + 32 * KSPL];  // 157.5 KB
    __shared__ float projL[3][128];
    __shared__ int s_place;

    const int tid = threadIdx.x;

    // ---- self-placement: XCD id + column slot (proven r8/r10-r13) ----
    {
        unsigned int xcc_raw;
        asm volatile("s_getreg_b32 %0, hwreg(HW_REG_XCC_ID)" : "=s"(xcc_raw));
        if (tid == 0) {
            int slot = atomicAdd(&xcdctr[xcc_raw & 7], 1);
            s_place = (int)((xcc_raw & 7) << 5) | (slot & 31);
        }
    }
    __syncthreads();
    const int xcc = s_place >> 5;   // 0..7  -> rows xcc*32..+31
    const int cw  = s_place & 31;   // 0..31 -> hcols cw*32..+31
    const int hc0 = cw * 32;

    // ---- one-time LDS fill: gates 0,1 full K (XOR-swizzled) ----
    {
        const int q2 = tid & 63;           // g*32 + hcol_local
        const int g = q2 >> 5;
        const int hl_ = q2 & 31;
        const int j = hc0 + hl_;
        const int xq = (hl_ & 7) << 3;
        const unsigned short* src = WhT + ((size_t)g << 20) + (size_t)j * 1024;
        const int kb0 = (tid >> 6) * 256;
        #pragma unroll
        for (int it = 0; it < 32; ++it) {
            int k = kb0 + 8 * it;
            *(short8*)(Blds + (size_t)(g * 32 + hl_) * 1024 + (k ^ xq)) =
                *(const short8*)(src + k);
        }
    }
    // ---- one-time LDS fill: gate 2, k in [0, KSPL) ----
    {
        const unsigned short* src2 = WhT + ((size_t)2 << 20);
        unsigned short* G2 = Blds + 64 * 1024;
        for (int idx = tid; idx < 32 * (KSPL / 8); idx += 256) {  // 1792
            int col = idx / (KSPL / 8);
            int k = (idx - col * (KSPL / 8)) * 8;
            int xq = (col & 7) << 3;
            *(short8*)(G2 + (size_t)col * KSPL + (k ^ xq)) =
                *(const short8*)(src2 + (size_t)(hc0 + col) * 1024 + k);
        }
    }
    for (int idx = tid; idx < 384; idx += 256) {
        int v = idx >> 7, q = idx & 127;
        projL[v][q] = proj3[(size_t)v * 4096 + (size_t)(q >> 5) * 1024 + hc0 + (q & 31)];
    }
    __syncthreads();

    // ---- wave/lane geometry (r10-r13-proven) ----
    const int w = tid >> 6;
    const int wr = w >> 1;             // row-slab 0,1 (16 rows)
    const int wc = w & 1;              // hcol-group 0,1 (16 hcols)
    const int lane = tid & 63;
    const int lr = lane & 15;
    const int kq = lane >> 4;          // 0..3
    const int R0 = xcc * 32 + 16 * wr;
    const int hl = 16 * wc + lr;       // hcol_local 0..31
    const int xorq = (hl & 7) << 3;
    const size_t abase = (size_t)(R0 + lr) * H_ + 8 * kq;
    const int crow0 = R0 + 4 * kq;

    const unsigned short* BL0 = Blds + (size_t)hl * 1024;          // gate 0
    const unsigned short* BL1 = Blds + (size_t)(32 + hl) * 1024;   // gate 1
    const unsigned short* BL2 = Blds + 64 * 1024 + (size_t)hl * KSPL;  // gate 2 head
    const unsigned short* BS2 = WhT + ((size_t)2 << 20) + (size_t)(hc0 + hl) * 1024 + 8 * kq;
    const unsigned short* BS3 = WhT + ((size_t)3 << 20) + (size_t)(hc0 + hl) * 1024 + 8 * kq;

    float creg[4] = {0.f, 0.f, 0.f, 0.f};
    unsigned short* hbuf[2] = {hb0, hb1};

    for (int t = 0; t < T_; ++t) {
        const unsigned short* h_in = hbuf[t & 1];
        unsigned short* h_out = hbuf[(t + 1) & 1];

        // tokens: immutable input, issue before the poll
        int tok[4];
        #pragma unroll
        for (int i = 0; i < 4; ++i)
            tok[i] = x[(size_t)(crow0 + i) * T_ + t];

        if (t > 0) {
            // tid0 polls the single per-XCD counter at the LLC (proven path)
            if (tid == 0) {
                const int* cp = cnt + ((size_t)(t - 1) * 8 + xcc) * 32;
                while (__hip_atomic_load(cp, __ATOMIC_RELAXED,
                                         __HIP_MEMORY_SCOPE_AGENT) < 32) {
                    __builtin_amdgcn_s_sleep(1);
                }
            }
            __syncthreads();                // release all 4 waves
            asm volatile("" ::: "memory");  // no data-load hoisting above poll
        }

        // ---- GEMM with chunked sc0 A-pipeline: 4 chunks x 8 k2 ----
        // sc0 loads bypass vL1, served by shared XCD L2 (fresh h).
        const unsigned short* aptr = h_in + abase;
        short8 afA[8], afB[8];

        // issue chunk 0 -> afA
        #pragma unroll
        for (int j = 0; j < 8; ++j)
            asm volatile("global_load_dwordx4 %0, %1, off offset:%2 sc0"
                         : "=&v"(afA[j]) : "v"(aptr), "n"(64 * j));

        floatx4 acc[4] = {};
        #pragma unroll
        for (int c = 0; c < 4; ++c) {
            // issue next chunk into the other buffer
            if (c < 3) {
                if ((c & 1) == 0) {
                    #pragma unroll
                    for (int j = 0; j < 8; ++j)
                        asm volatile("global_load_dwordx4 %0, %1, off offset:%2 sc0"
                                     : "=&v"(afB[j]) : "v"(aptr), "n"(64 * (8 * (c + 1) + j)));
                } else {
                    #pragma unroll
                    for (int j = 0; j < 8; ++j)
                        asm volatile("global_load_dwordx4 %0, %1, off offset:%2 sc0"
                                     : "=&v"(afA[j]) : "v"(aptr), "n"(64 * (8 * (c + 1) + j)));
                }
                __builtin_amdgcn_sched_barrier(0);
                asm volatile("s_waitcnt vmcnt(8)" ::: "memory");  // chunk c retired
                __builtin_amdgcn_sched_barrier(0);
            } else {
                __builtin_amdgcn_sched_barrier(0);
                asm volatile("s_waitcnt vmcnt(0)" ::: "memory");
                __builtin_amdgcn_sched_barrier(0);
            }
            #pragma unroll
            for (int j = 0; j < 8; ++j) {
                const int k2 = 8 * c + j;
                const short8 a = ((c & 1) == 0) ? afA[j] : afB[j];
                const int ki = (32 * k2 + 8 * kq) ^ xorq;
                short8 b0 = *(const short8*)(BL0 + ki);
                short8 b1 = *(const short8*)(BL1 + ki);
                short8 b2, b3;
                if (k2 < 14) b2 = *(const short8*)(BL2 + ki);
                else         b2 = *(const short8*)(BS2 + 32 * k2);
                b3 = *(const short8*)(BS3 + 32 * k2);
                acc[0] = __builtin_amdgcn_mfma_f32_16x16x32_bf16(a, b0, acc[0], 0, 0, 0);
                acc[1] = __builtin_amdgcn_mfma_f32_16x16x32_bf16(a, b1, acc[1], 0, 0, 0);
                acc[2] = __builtin_amdgcn_mfma_f32_16x16x32_bf16(a, b2, acc[2], 0, 0, 0);
                acc[3] = __builtin_amdgcn_mfma_f32_16x16x32_bf16(a, b3, acc[3], 0, 0, 0);
            }
        }

        // ---- in-register combine; plain 2B stores (land in shared L2) ----
        #pragma unroll
        for (int i = 0; i < 4; ++i) {
            const float* pl = projL[tok[i]];
            float zg = fast_tanh(acc[0][i] + pl[hl]);
            float zi = fast_tanh(acc[1][i] + pl[32 + hl]);
            float zf = fast_tanh(acc[2][i] + pl[64 + hl]);
            float zo = fast_tanh(acc[3][i] + pl[96 + hl]);
            float cv = zg * zi + creg[i] * zf;
            creg[i] = cv;
            h_out[(size_t)(crow0 + i) * H_ + hc0 + hl] = f2bf(fast_tanh(cv) * zo);
        }

        if (t == T_ - 1) break;  // end-of-dispatch release covers lstm_final

        // ---- release: h stores acked at L2 -> one atomicAdd at the LLC ----
        asm volatile("s_waitcnt vmcnt(0)" ::: "memory");
        __syncthreads();  // all 4 waves' stores drained
        if (tid == 0)
            __hip_atomic_fetch_add(cnt + ((size_t)t * 8 + xcc) * 32, 1,
                                   __ATOMIC_RELAXED, __HIP_MEMORY_SCOPE_AGENT);
    }
}

// ---------------------------------------------------------------------------
// Final projection + log_softmax. One block (64 threads) per batch row.
// ---------------------------------------------------------------------------
__global__ void lstm_final(const unsigned short* __restrict__ h,
                           const float* __restrict__ Wp,
                           const float* __restrict__ bp,
                           float* __restrict__ out) {
    int row = blockIdx.x;
    int lane = threadIdx.x;
    float acc[C_];
    #pragma unroll
    for (int cc = 0; cc < C_; ++cc) acc[cc] = 0.f;
    for (int k = lane; k < H_; k += 64) {
        float hv = bf2f(h[(size_t)row * H_ + k]);
        #pragma unroll
        for (int cc = 0; cc < C_; ++cc) acc[cc] += hv * Wp[(size_t)k * C_ + cc];
    }
    #pragma unroll
    for (int cc = 0; cc < C_; ++cc)
        #pragma unroll
        for (int off = 32; off > 0; off >>= 1)
            acc[cc] += __shfl_down(acc[cc], off);
    if (lane == 0) {
        float p[C_];
        float m = -1e30f;
        #pragma unroll
        for (int cc = 0; cc < C_; ++cc) {
            p[cc] = acc[cc] + bp[cc];
            m = fmaxf(m, p[cc]);
        }
        float se = 0.f;
        #pragma unroll
        for (int cc = 0; cc < C_; ++cc) se += expf(p[cc] - m);
        float lse = m + logf(se);
        #pragma unroll
        for (int cc = 0; cc < C_; ++cc) out[(size_t)row * C_ + cc] = p[cc] - lse;
    }
}

extern "C" void kernel_launch(void* const* d_in, const int* in_sizes, int n_in,
                              void* d_out, int out_size, void* d_ws, size_t ws_size,
                              hipStream_t stream) {
    const int* x = (const int*)d_in[0];
    const float* emb = (const float*)d_in[1];
    const float* W_gx = (const float*)d_in[2];
    const float* W_gh = (const float*)d_in[3];
    const float* b_g = (const float*)d_in[4];
    const float* W_ix = (const float*)d_in[5];
    const float* W_ih = (const float*)d_in[6];
    const float* b_i = (const float*)d_in[7];
    const float* W_fx = (const float*)d_in[8];
    const float* W_fh = (const float*)d_in[9];
    const float* b_f = (const float*)d_in[10];
    const float* W_ox = (const float*)d_in[11];
    const float* W_oh = (const float*)d_in[12];
    const float* b_o = (const float*)d_in[13];
    const float* W_ph = (const float*)d_in[14];
    const float* b_p = (const float*)d_in[15];
    float* out = (float*)d_out;

    // workspace layout
    char* ws = (char*)d_ws;
    unsigned short* WhT = (unsigned short*)ws;                   // 8 MB
    size_t off = (size_t)4 * 1024 * 1024 * 2;
    float* proj3 = (float*)(ws + off); off += 3 * 4096 * 4;      // 48 KB
    unsigned short* hbuf0 = (unsigned short*)(ws + off); off += (size_t)B_ * H_ * 2;
    unsigned short* hbuf1 = (unsigned short*)(ws + off); off += (size_t)B_ * H_ * 2;
    int* cnt = (int*)(ws + off); off += (size_t)T_ * 8 * 32 * 4;  // 512 KB
    int* xcdctr = (int*)(ws + off); off += 8 * sizeof(int);

    // 1. pack WhT (bf16, transposed)
    lstm_pack_wht<<<dim3(32, 32, 4), 256, 0, stream>>>(W_gh, W_ih, W_fh, W_oh, WhT);
    // 2. proj3 = emb @ Wx + b
    lstm_proj3<<<dim3(16, 3), 256, 0, stream>>>(emb, W_gx, W_ix, W_fx, W_ox,
                                                b_g, b_i, b_f, b_o, proj3);
    // 3. zero h0, counters (every launch -> replay-safe)
    hipMemsetAsync(hbuf0, 0, (size_t)B_ * H_ * 2, stream);
    hipMemsetAsync(cnt, 0, (size_t)T_ * 8 * 32 * 4, stream);
    hipMemsetAsync(xcdctr, 0, 8 * sizeof(int), stream);

    // 4. persistent recurrence (cooperative: all 256 WGs co-resident)
    {
        const unsigned short* a0 = WhT;
        const float* a1 = proj3; const int* a2 = x;
        unsigned short* a3 = hbuf0; unsigned short* a4 = hbuf1;
        int* a5 = cnt; int* a6 = xcdctr;
        void* args[] = {&a0, &a1, &a2, &a3, &a4, &a5, &a6};
        hipLaunchCooperativeKernel((const void*)lstm_persist, dim3(256), dim3(256),
                                   args, 0, stream);
    }

    // 5. final projection + log_softmax (h_512 lands in hbuf0: T_ even)
    lstm_final<<<B_, 64, 0, stream>>>(hbuf0, W_ph, b_p, out);
}